// Round 10
// baseline (94.114 us; speedup 1.0000x reference)
//
#include <hip/hip_runtime.h>
#include <hip/hip_bf16.h>
#include <stdint.h>

#define N_ROWS 16384
#define O_ROWS 1024
#define K_DIM  512

typedef __bf16 bf16x8 __attribute__((ext_vector_type(8)));
typedef float  f32x4  __attribute__((ext_vector_type(4)));

__device__ __forceinline__ ushort f2bfu(float f) {
    __bf16 h = (__bf16)f;
    return __builtin_bit_cast(ushort, h);
}

// ---------------------------------------------------------------------------
// Round 10 = round 9 + T14 register prefetch, 512-thread blocks.
//  - Same 128x128 tile, BK=64, T2 XOR-swizzle, XCD swizzle, extended-K-tile.
//  - 8 waves (2x4 grid), each wave 64x32 out: acc 4x2 frags (32 VGPR).
//  - Per thread stages 2 rows x 8 floats per matrix per K-step: the full
//    next-tile prefetch is 8x f32x4 = 32 VGPR, issued right after bar1 so
//    HBM latency hides under the MFMA phase + bar2 + cvt instead of
//    serializing (r9 was latency-bound: Mfma 9%, VALU 26%, HBM 16%).
// ---------------------------------------------------------------------------
__global__ __launch_bounds__(512) void quadra_kernel(
    const float* __restrict__ x, const float* __restrict__ mean,
    float* __restrict__ out)
{
    __shared__ ushort sA[128 * 64];   // [row][k] bf16 (swizzled), 16 KiB
    __shared__ ushort sB[128 * 64];   // [orow][k] bf16 -2*mean (swizzled), 16 KiB

    const int bid  = blockIdx.x;                // 0..1023
    const int t    = (bid & 7) * 128 + (bid >> 3);
    const int brow = (t >> 3) * 128;
    const int bcol = (t & 7) * 128;

    const int tid  = threadIdx.x;
    const int lane = tid & 63;
    const int wid  = tid >> 6;                  // 0..7
    const int wr = wid >> 2, wc = wid & 3;      // 2x4 wave grid, 64x32 out each

    f32x4 acc[4][2] = {};

    // staging: srow = tid>>3 (0..63), q = tid&7. Thread stages rows
    // {srow, srow+64}, k-octet [q*8, q*8+8) per 64-wide K-tile.
    const int srow = tid >> 3;
    const int q    = tid & 7;

    const float* gA = x    + (size_t)(brow + srow) * K_DIM + q * 8;
    const float* gB = mean + (size_t)(bcol + srow) * K_DIM + q * 8;

    float asq[2] = {0.f, 0.f}, bsq[2] = {0.f, 0.f};

    // prologue prefetch (kt = 0)
    f32x4 pa[2][2], pb[2][2];
    #pragma unroll
    for (int r2 = 0; r2 < 2; ++r2) {
        const float* pA = gA + (size_t)(r2 * 64) * K_DIM;
        const float* pB = gB + (size_t)(r2 * 64) * K_DIM;
        pa[r2][0] = *(const f32x4*)(pA);
        pa[r2][1] = *(const f32x4*)(pA + 4);
        pb[r2][0] = *(const f32x4*)(pB);
        pb[r2][1] = *(const f32x4*)(pB + 4);
    }

    const int hi = lane >> 4, cl = lane & 15;

    #pragma unroll
    for (int kt = 0; kt < 8; ++kt) {
        // consume prefetched regs: sumsq + cvt + single ds_write_b128 per row
        #pragma unroll
        for (int r2 = 0; r2 < 2; ++r2) {
            f32x4 a0 = pa[r2][0], a1 = pa[r2][1];
            f32x4 b0 = pb[r2][0], b1 = pb[r2][1];

            asq[r2] += a0[0]*a0[0] + a0[1]*a0[1] + a0[2]*a0[2] + a0[3]*a0[3]
                     + a1[0]*a1[0] + a1[1]*a1[1] + a1[2]*a1[2] + a1[3]*a1[3];
            bsq[r2] += b0[0]*b0[0] + b0[1]*b0[1] + b0[2]*b0[2] + b0[3]*b0[3]
                     + b1[0]*b1[0] + b1[1]*b1[1] + b1[2]*b1[2] + b1[3]*b1[3];

            bf16x8 ca, cb;
            ca[0] = (__bf16)a0[0]; ca[1] = (__bf16)a0[1];
            ca[2] = (__bf16)a0[2]; ca[3] = (__bf16)a0[3];
            ca[4] = (__bf16)a1[0]; ca[5] = (__bf16)a1[1];
            ca[6] = (__bf16)a1[2]; ca[7] = (__bf16)a1[3];
            cb[0] = (__bf16)(b0[0] * -2.0f); cb[1] = (__bf16)(b0[1] * -2.0f);
            cb[2] = (__bf16)(b0[2] * -2.0f); cb[3] = (__bf16)(b0[3] * -2.0f);
            cb[4] = (__bf16)(b1[0] * -2.0f); cb[5] = (__bf16)(b1[1] * -2.0f);
            cb[6] = (__bf16)(b1[2] * -2.0f); cb[7] = (__bf16)(b1[3] * -2.0f);

            const int row = srow + r2 * 64;
            const int wb  = (q * 16) ^ ((row & 7) << 4);   // byte offset, 16B-aligned
            *(bf16x8*)(sA + row * 64 + (wb >> 1)) = ca;
            *(bf16x8*)(sB + row * 64 + (wb >> 1)) = cb;
        }
        __syncthreads();

        // issue next-tile loads NOW: they fly during the MFMA phase + bar2
        if (kt < 7) {
            #pragma unroll
            for (int r2 = 0; r2 < 2; ++r2) {
                const float* pA = gA + (size_t)(r2 * 64) * K_DIM + (kt + 1) * 64;
                const float* pB = gB + (size_t)(r2 * 64) * K_DIM + (kt + 1) * 64;
                pa[r2][0] = *(const f32x4*)(pA);
                pa[r2][1] = *(const f32x4*)(pA + 4);
                pb[r2][0] = *(const f32x4*)(pB);
                pb[r2][1] = *(const f32x4*)(pB + 4);
            }
        }

        #pragma unroll
        for (int ks = 0; ks < 2; ++ks) {
            bf16x8 a[4], b[2];
            #pragma unroll
            for (int m = 0; m < 4; ++m) {
                const int row = wr*64 + m*16 + cl;
                const int rb  = (ks*64 + hi*16) ^ ((row & 7) << 4);
                a[m] = *(const bf16x8*)(sA + row * 64 + (rb >> 1));
            }
            #pragma unroll
            for (int n = 0; n < 2; ++n) {
                const int row = wc*32 + n*16 + cl;
                const int rb  = (ks*64 + hi*16) ^ ((row & 7) << 4);
                b[n] = *(const bf16x8*)(sB + row * 64 + (rb >> 1));
            }
            #pragma unroll
            for (int m = 0; m < 4; ++m)
                #pragma unroll
                for (int n = 0; n < 2; ++n)
                    acc[m][n] = __builtin_amdgcn_mfma_f32_16x16x32_bf16(
                        a[m], b[n], acc[m][n], 0, 0, 0);
        }
        __syncthreads();
    }

    // Extended K-tile (aliased into sA, dead after the main loop):
    //   sAe[row] = [xsq, 1, 0 x30]   sBe[row] = [1, msq, 0 x30]
    ushort* sAe = sA;
    ushort* sBe = sA + 128 * 32;
    #pragma unroll
    for (int r2 = 0; r2 < 2; ++r2) {
        float sa = asq[r2], sb = bsq[r2];
        #pragma unroll
        for (int msk = 1; msk < 8; msk <<= 1) {
            sa += __shfl_xor(sa, msk);
            sb += __shfl_xor(sb, msk);
        }
        const int row = srow + r2 * 64;
        uint2 aw = {0u, 0u}, bw = {0u, 0u};
        if (q == 0) {
            aw.x = (uint32_t)f2bfu(sa) | (0x3F80u << 16);   // [xsq, 1.0]
            bw.x = 0x3F80u | ((uint32_t)f2bfu(sb) << 16);   // [1.0, msq]
        }
        *(uint2*)(sAe + row * 32 + q * 4) = aw;
        *(uint2*)(sBe + row * 32 + q * 4) = bw;
    }
    __syncthreads();

    {   // extra MFMA: adds xsq[r] + msq[o] into every accumulator element
        bf16x8 a[4], b[2];
        #pragma unroll
        for (int m = 0; m < 4; ++m)
            a[m] = *(const bf16x8*)(sAe + (wr*64 + m*16 + cl) * 32 + hi * 8);
        #pragma unroll
        for (int n = 0; n < 2; ++n)
            b[n] = *(const bf16x8*)(sBe + (wc*32 + n*16 + cl) * 32 + hi * 8);
        #pragma unroll
        for (int m = 0; m < 4; ++m)
            #pragma unroll
            for (int n = 0; n < 2; ++n)
                acc[m][n] = __builtin_amdgcn_mfma_f32_16x16x32_bf16(
                    a[m], b[n], acc[m][n], 0, 0, 0);
    }

    // epilogue: C/D layout col = lane&15, row = (lane>>4)*4 + j
    const int rg = lane >> 4;
    #pragma unroll
    for (int m = 0; m < 4; ++m) {
        #pragma unroll
        for (int j = 0; j < 4; ++j) {
            const int grow = brow + wr*64 + m*16 + rg*4 + j;
            float* orow = out + (size_t)grow * O_ROWS + bcol + wc*32 + cl;
            #pragma unroll
            for (int n = 0; n < 2; ++n)
                orow[n * 16] = rsqrtf(acc[m][n][j]);
        }
    }
}

extern "C" void kernel_launch(void* const* d_in, const int* in_sizes, int n_in,
                              void* d_out, int out_size, void* d_ws, size_t ws_size,
                              hipStream_t stream) {
    const float* x    = (const float*)d_in[0];
    const float* mean = (const float*)d_in[1];
    float* out = (float*)d_out;

    quadra_kernel<<<dim3((N_ROWS / 128) * (O_ROWS / 128)), 512, 0, stream>>>(
        x, mean, out);
}

// Round 12
// 45.783 us; speedup vs baseline: 2.0557x; 2.0557x over previous
//
#include <hip/hip_runtime.h>
#include <hip/hip_bf16.h>
#include <stdint.h>

#define N_ROWS 16384
#define O_ROWS 1024
#define K_DIM  512

typedef __bf16 bf16x8 __attribute__((ext_vector_type(8)));
typedef float  f32x4  __attribute__((ext_vector_type(4)));

__device__ __forceinline__ ushort f2bfu(float f) {
    __bf16 h = (__bf16)f;
    return __builtin_bit_cast(ushort, h);
}

// ---------------------------------------------------------------------------
// Round 12 = round 11 resubmitted verbatim (r11 died to the same unresponsive
// MI355X container as r7/r8 before the bench could run).
// r11 = r10 with the kt loop pinned to NO unroll (#pragma unroll 1):
// r10's full unroll made 8 pipeline stages' prefetch state co-live -> spill
// (WRITE 65->203 MB, FETCH 33->118 MB). One iteration's live set (~100 VGPR)
// fits without spilling.
//  - 128x128 tile, BK=64, T2 XOR-swizzle, XCD swizzle, extended-K-tile.
//  - 512 threads, 2x4 wave grid, acc 4x2 frags; per-thread T14 prefetch
//    (8x f32x4 = 32 VGPR) issued right after bar1, consumed next iteration.
// ---------------------------------------------------------------------------
__global__ __launch_bounds__(512) void quadra_kernel(
    const float* __restrict__ x, const float* __restrict__ mean,
    float* __restrict__ out)
{
    __shared__ ushort sA[128 * 64];   // [row][k] bf16 (swizzled), 16 KiB
    __shared__ ushort sB[128 * 64];   // [orow][k] bf16 -2*mean (swizzled), 16 KiB

    const int bid  = blockIdx.x;                // 0..1023
    const int t    = (bid & 7) * 128 + (bid >> 3);
    const int brow = (t >> 3) * 128;
    const int bcol = (t & 7) * 128;

    const int tid  = threadIdx.x;
    const int lane = tid & 63;
    const int wid  = tid >> 6;                  // 0..7
    const int wr = wid >> 2, wc = wid & 3;      // 2x4 wave grid, 64x32 out each

    f32x4 acc[4][2] = {};

    // staging: srow = tid>>3 (0..63), q = tid&7. Thread stages rows
    // {srow, srow+64}, k-octet [q*8, q*8+8) per 64-wide K-tile.
    const int srow = tid >> 3;
    const int q    = tid & 7;

    const float* gA = x    + (size_t)(brow + srow) * K_DIM + q * 8;
    const float* gB = mean + (size_t)(bcol + srow) * K_DIM + q * 8;

    float asq[2] = {0.f, 0.f}, bsq[2] = {0.f, 0.f};

    // prologue prefetch (kt = 0)
    f32x4 pa[2][2], pb[2][2];
    #pragma unroll
    for (int r2 = 0; r2 < 2; ++r2) {
        const float* pA = gA + (size_t)(r2 * 64) * K_DIM;
        const float* pB = gB + (size_t)(r2 * 64) * K_DIM;
        pa[r2][0] = *(const f32x4*)(pA);
        pa[r2][1] = *(const f32x4*)(pA + 4);
        pb[r2][0] = *(const f32x4*)(pB);
        pb[r2][1] = *(const f32x4*)(pB + 4);
    }

    const int hi = lane >> 4, cl = lane & 15;

    #pragma unroll 1
    for (int kt = 0; kt < 8; ++kt) {
        // consume prefetched regs: sumsq + cvt + single ds_write_b128 per row
        #pragma unroll
        for (int r2 = 0; r2 < 2; ++r2) {
            f32x4 a0 = pa[r2][0], a1 = pa[r2][1];
            f32x4 b0 = pb[r2][0], b1 = pb[r2][1];

            asq[r2] += a0[0]*a0[0] + a0[1]*a0[1] + a0[2]*a0[2] + a0[3]*a0[3]
                     + a1[0]*a1[0] + a1[1]*a1[1] + a1[2]*a1[2] + a1[3]*a1[3];
            bsq[r2] += b0[0]*b0[0] + b0[1]*b0[1] + b0[2]*b0[2] + b0[3]*b0[3]
                     + b1[0]*b1[0] + b1[1]*b1[1] + b1[2]*b1[2] + b1[3]*b1[3];

            bf16x8 ca, cb;
            ca[0] = (__bf16)a0[0]; ca[1] = (__bf16)a0[1];
            ca[2] = (__bf16)a0[2]; ca[3] = (__bf16)a0[3];
            ca[4] = (__bf16)a1[0]; ca[5] = (__bf16)a1[1];
            ca[6] = (__bf16)a1[2]; ca[7] = (__bf16)a1[3];
            cb[0] = (__bf16)(b0[0] * -2.0f); cb[1] = (__bf16)(b0[1] * -2.0f);
            cb[2] = (__bf16)(b0[2] * -2.0f); cb[3] = (__bf16)(b0[3] * -2.0f);
            cb[4] = (__bf16)(b1[0] * -2.0f); cb[5] = (__bf16)(b1[1] * -2.0f);
            cb[6] = (__bf16)(b1[2] * -2.0f); cb[7] = (__bf16)(b1[3] * -2.0f);

            const int row = srow + r2 * 64;
            const int wb  = (q * 16) ^ ((row & 7) << 4);   // byte offset, 16B slot
            *(bf16x8*)(sA + row * 64 + (wb >> 1)) = ca;
            *(bf16x8*)(sB + row * 64 + (wb >> 1)) = cb;
        }
        __syncthreads();

        // issue next-tile loads NOW: they fly during the MFMA phase + bar2
        if (kt < 7) {
            #pragma unroll
            for (int r2 = 0; r2 < 2; ++r2) {
                const float* pA = gA + (size_t)(r2 * 64) * K_DIM + (kt + 1) * 64;
                const float* pB = gB + (size_t)(r2 * 64) * K_DIM + (kt + 1) * 64;
                pa[r2][0] = *(const f32x4*)(pA);
                pa[r2][1] = *(const f32x4*)(pA + 4);
                pb[r2][0] = *(const f32x4*)(pB);
                pb[r2][1] = *(const f32x4*)(pB + 4);
            }
        }

        #pragma unroll
        for (int ks = 0; ks < 2; ++ks) {
            bf16x8 a[4], b[2];
            #pragma unroll
            for (int m = 0; m < 4; ++m) {
                const int row = wr*64 + m*16 + cl;
                const int rb  = (ks*64 + hi*16) ^ ((row & 7) << 4);
                a[m] = *(const bf16x8*)(sA + row * 64 + (rb >> 1));
            }
            #pragma unroll
            for (int n = 0; n < 2; ++n) {
                const int row = wc*32 + n*16 + cl;
                const int rb  = (ks*64 + hi*16) ^ ((row & 7) << 4);
                b[n] = *(const bf16x8*)(sB + row * 64 + (rb >> 1));
            }
            #pragma unroll
            for (int m = 0; m < 4; ++m)
                #pragma unroll
                for (int n = 0; n < 2; ++n)
                    acc[m][n] = __builtin_amdgcn_mfma_f32_16x16x32_bf16(
                        a[m], b[n], acc[m][n], 0, 0, 0);
        }
        __syncthreads();
    }

    // Extended K-tile (aliased into sA, dead after the main loop):
    //   sAe[row] = [xsq, 1, 0 x30]   sBe[row] = [1, msq, 0 x30]
    ushort* sAe = sA;
    ushort* sBe = sA + 128 * 32;
    #pragma unroll
    for (int r2 = 0; r2 < 2; ++r2) {
        float sa = asq[r2], sb = bsq[r2];
        #pragma unroll
        for (int msk = 1; msk < 8; msk <<= 1) {
            sa += __shfl_xor(sa, msk);
            sb += __shfl_xor(sb, msk);
        }
        const int row = srow + r2 * 64;
        uint2 aw = {0u, 0u}, bw = {0u, 0u};
        if (q == 0) {
            aw.x = (uint32_t)f2bfu(sa) | (0x3F80u << 16);   // [xsq, 1.0]
            bw.x = 0x3F80u | ((uint32_t)f2bfu(sb) << 16);   // [1.0, msq]
        }
        *(uint2*)(sAe + row * 32 + q * 4) = aw;
        *(uint2*)(sBe + row * 32 + q * 4) = bw;
    }
    __syncthreads();

    {   // extra MFMA: adds xsq[r] + msq[o] into every accumulator element
        bf16x8 a[4], b[2];
        #pragma unroll
        for (int m = 0; m < 4; ++m)
            a[m] = *(const bf16x8*)(sAe + (wr*64 + m*16 + cl) * 32 + hi * 8);
        #pragma unroll
        for (int n = 0; n < 2; ++n)
            b[n] = *(const bf16x8*)(sBe + (wc*32 + n*16 + cl) * 32 + hi * 8);
        #pragma unroll
        for (int m = 0; m < 4; ++m)
            #pragma unroll
            for (int n = 0; n < 2; ++n)
                acc[m][n] = __builtin_amdgcn_mfma_f32_16x16x32_bf16(
                    a[m], b[n], acc[m][n], 0, 0, 0);
    }

    // epilogue: C/D layout col = lane&15, row = (lane>>4)*4 + j
    const int rg = lane >> 4;
    #pragma unroll
    for (int m = 0; m < 4; ++m) {
        #pragma unroll
        for (int j = 0; j < 4; ++j) {
            const int grow = brow + wr*64 + m*16 + rg*4 + j;
            float* orow = out + (size_t)grow * O_ROWS + bcol + wc*32 + cl;
            #pragma unroll
            for (int n = 0; n < 2; ++n)
                orow[n * 16] = rsqrtf(acc[m][n][j]);
        }
    }
}

extern "C" void kernel_launch(void* const* d_in, const int* in_sizes, int n_in,
                              void* d_out, int out_size, void* d_ws, size_t ws_size,
                              hipStream_t stream) {
    const float* x    = (const float*)d_in[0];
    const float* mean = (const float*)d_in[1];
    float* out = (float*)d_out;

    quadra_kernel<<<dim3((N_ROWS / 128) * (O_ROWS / 128)), 512, 0, stream>>>(
        x, mean, out);
}

// Round 14
// 45.495 us; speedup vs baseline: 2.0687x; 1.0063x over previous
//
#include <hip/hip_runtime.h>
#include <hip/hip_bf16.h>
#include <stdint.h>

#define N_ROWS 16384
#define O_ROWS 1024
#define K_DIM  512

typedef __bf16 bf16x8 __attribute__((ext_vector_type(8)));
typedef float  f32x4  __attribute__((ext_vector_type(4)));

__device__ __forceinline__ ushort f2bfu(float f) {
    __bf16 h = (__bf16)f;
    return __builtin_bit_cast(ushort, h);
}

// Raw barrier: drain only LDS ops (lgkmcnt). Unlike __syncthreads (which
// emits s_waitcnt vmcnt(0) lgkmcnt(0)), this lets register-destined global
// prefetch loads stay IN FLIGHT across the barrier; the compiler waits for
// them with counted vmcnt at first use (next iteration's convert phase).
// No global-memory communication happens inside the kernel, so vmcnt drain
// at barriers is not needed for correctness.
#define BAR_LGKM()  do {                                        \
    asm volatile("s_waitcnt lgkmcnt(0)" ::: "memory");          \
    __builtin_amdgcn_s_barrier();                               \
} while (0)

// ---------------------------------------------------------------------------
// Round 14 = round 13 resubmitted verbatim (r13 died to the same unresponsive
// MI355X container as r7/r8/r11 before the bench could run).
// r13 = r12 + T4-lite barriers (lgkm-only drain) + prefetch issued before bar1.
// r12 (45.8 us) was phase-serialized: __syncthreads' vmcnt(0) drained the
// T14 prefetch at bar2 every iteration, re-exposing HBM latency. With raw
// lgkm-only barriers the loads span bar1+MFMA+bar2+next-stage.
//  - 128x128 tile, BK=64, T2 XOR-swizzle, XCD swizzle, extended-K-tile.
//  - 512 threads, 2x4 wave grid, acc 4x2 frags; prefetch 8x f32x4 = 32 VGPR.
// ---------------------------------------------------------------------------
__global__ __launch_bounds__(512) void quadra_kernel(
    const float* __restrict__ x, const float* __restrict__ mean,
    float* __restrict__ out)
{
    __shared__ ushort sA[128 * 64];   // [row][k] bf16 (swizzled), 16 KiB
    __shared__ ushort sB[128 * 64];   // [orow][k] bf16 -2*mean (swizzled), 16 KiB

    const int bid  = blockIdx.x;                // 0..1023
    const int t    = (bid & 7) * 128 + (bid >> 3);
    const int brow = (t >> 3) * 128;
    const int bcol = (t & 7) * 128;

    const int tid  = threadIdx.x;
    const int lane = tid & 63;
    const int wid  = tid >> 6;                  // 0..7
    const int wr = wid >> 2, wc = wid & 3;      // 2x4 wave grid, 64x32 out each

    f32x4 acc[4][2] = {};

    // staging: srow = tid>>3 (0..63), q = tid&7. Thread stages rows
    // {srow, srow+64}, k-octet [q*8, q*8+8) per 64-wide K-tile.
    const int srow = tid >> 3;
    const int q    = tid & 7;

    const float* gA = x    + (size_t)(brow + srow) * K_DIM + q * 8;
    const float* gB = mean + (size_t)(bcol + srow) * K_DIM + q * 8;

    float asq[2] = {0.f, 0.f}, bsq[2] = {0.f, 0.f};

    // prologue prefetch (kt = 0)
    f32x4 pa[2][2], pb[2][2];
    #pragma unroll
    for (int r2 = 0; r2 < 2; ++r2) {
        const float* pA = gA + (size_t)(r2 * 64) * K_DIM;
        const float* pB = gB + (size_t)(r2 * 64) * K_DIM;
        pa[r2][0] = *(const f32x4*)(pA);
        pa[r2][1] = *(const f32x4*)(pA + 4);
        pb[r2][0] = *(const f32x4*)(pB);
        pb[r2][1] = *(const f32x4*)(pB + 4);
    }

    const int hi = lane >> 4, cl = lane & 15;

    #pragma unroll 1
    for (int kt = 0; kt < 8; ++kt) {
        // consume prefetched regs: sumsq + cvt + single ds_write_b128 per row
        #pragma unroll
        for (int r2 = 0; r2 < 2; ++r2) {
            f32x4 a0 = pa[r2][0], a1 = pa[r2][1];
            f32x4 b0 = pb[r2][0], b1 = pb[r2][1];

            asq[r2] += a0[0]*a0[0] + a0[1]*a0[1] + a0[2]*a0[2] + a0[3]*a0[3]
                     + a1[0]*a1[0] + a1[1]*a1[1] + a1[2]*a1[2] + a1[3]*a1[3];
            bsq[r2] += b0[0]*b0[0] + b0[1]*b0[1] + b0[2]*b0[2] + b0[3]*b0[3]
                     + b1[0]*b1[0] + b1[1]*b1[1] + b1[2]*b1[2] + b1[3]*b1[3];

            bf16x8 ca, cb;
            ca[0] = (__bf16)a0[0]; ca[1] = (__bf16)a0[1];
            ca[2] = (__bf16)a0[2]; ca[3] = (__bf16)a0[3];
            ca[4] = (__bf16)a1[0]; ca[5] = (__bf16)a1[1];
            ca[6] = (__bf16)a1[2]; ca[7] = (__bf16)a1[3];
            cb[0] = (__bf16)(b0[0] * -2.0f); cb[1] = (__bf16)(b0[1] * -2.0f);
            cb[2] = (__bf16)(b0[2] * -2.0f); cb[3] = (__bf16)(b0[3] * -2.0f);
            cb[4] = (__bf16)(b1[0] * -2.0f); cb[5] = (__bf16)(b1[1] * -2.0f);
            cb[6] = (__bf16)(b1[2] * -2.0f); cb[7] = (__bf16)(b1[3] * -2.0f);

            const int row = srow + r2 * 64;
            const int wb  = (q * 16) ^ ((row & 7) << 4);   // byte offset, 16B slot
            *(bf16x8*)(sA + row * 64 + (wb >> 1)) = ca;
            *(bf16x8*)(sB + row * 64 + (wb >> 1)) = cb;
        }

        // issue next-tile loads BEFORE bar1: with lgkm-only barriers they
        // stay in flight across bar1 + ds_read/MFMA + bar2, waited at the
        // next iteration's consume.
        if (kt < 7) {
            #pragma unroll
            for (int r2 = 0; r2 < 2; ++r2) {
                const float* pA = gA + (size_t)(r2 * 64) * K_DIM + (kt + 1) * 64;
                const float* pB = gB + (size_t)(r2 * 64) * K_DIM + (kt + 1) * 64;
                pa[r2][0] = *(const f32x4*)(pA);
                pa[r2][1] = *(const f32x4*)(pA + 4);
                pb[r2][0] = *(const f32x4*)(pB);
                pb[r2][1] = *(const f32x4*)(pB + 4);
            }
        }

        BAR_LGKM();   // bar1: ds_writes visible; prefetch NOT drained

        #pragma unroll
        for (int ks = 0; ks < 2; ++ks) {
            bf16x8 a[4], b[2];
            #pragma unroll
            for (int m = 0; m < 4; ++m) {
                const int row = wr*64 + m*16 + cl;
                const int rb  = (ks*64 + hi*16) ^ ((row & 7) << 4);
                a[m] = *(const bf16x8*)(sA + row * 64 + (rb >> 1));
            }
            #pragma unroll
            for (int n = 0; n < 2; ++n) {
                const int row = wc*32 + n*16 + cl;
                const int rb  = (ks*64 + hi*16) ^ ((row & 7) << 4);
                b[n] = *(const bf16x8*)(sB + row * 64 + (rb >> 1));
            }
            #pragma unroll
            for (int m = 0; m < 4; ++m)
                #pragma unroll
                for (int n = 0; n < 2; ++n)
                    acc[m][n] = __builtin_amdgcn_mfma_f32_16x16x32_bf16(
                        a[m], b[n], acc[m][n], 0, 0, 0);
        }

        BAR_LGKM();   // bar2: ds_reads complete; next iter may overwrite LDS
    }

    // Extended K-tile (aliased into sA, dead after the main loop):
    //   sAe[row] = [xsq, 1, 0 x30]   sBe[row] = [1, msq, 0 x30]
    ushort* sAe = sA;
    ushort* sBe = sA + 128 * 32;
    #pragma unroll
    for (int r2 = 0; r2 < 2; ++r2) {
        float sa = asq[r2], sb = bsq[r2];
        #pragma unroll
        for (int msk = 1; msk < 8; msk <<= 1) {
            sa += __shfl_xor(sa, msk);
            sb += __shfl_xor(sb, msk);
        }
        const int row = srow + r2 * 64;
        uint2 aw = {0u, 0u}, bw = {0u, 0u};
        if (q == 0) {
            aw.x = (uint32_t)f2bfu(sa) | (0x3F80u << 16);   // [xsq, 1.0]
            bw.x = 0x3F80u | ((uint32_t)f2bfu(sb) << 16);   // [1.0, msq]
        }
        *(uint2*)(sAe + row * 32 + q * 4) = aw;
        *(uint2*)(sBe + row * 32 + q * 4) = bw;
    }
    BAR_LGKM();

    {   // extra MFMA: adds xsq[r] + msq[o] into every accumulator element
        bf16x8 a[4], b[2];
        #pragma unroll
        for (int m = 0; m < 4; ++m)
            a[m] = *(const bf16x8*)(sAe + (wr*64 + m*16 + cl) * 32 + hi * 8);
        #pragma unroll
        for (int n = 0; n < 2; ++n)
            b[n] = *(const bf16x8*)(sBe + (wc*32 + n*16 + cl) * 32 + hi * 8);
        #pragma unroll
        for (int m = 0; m < 4; ++m)
            #pragma unroll
            for (int n = 0; n < 2; ++n)
                acc[m][n] = __builtin_amdgcn_mfma_f32_16x16x32_bf16(
                    a[m], b[n], acc[m][n], 0, 0, 0);
    }

    // epilogue: C/D layout col = lane&15, row = (lane>>4)*4 + j
    const int rg = lane >> 4;
    #pragma unroll
    for (int m = 0; m < 4; ++m) {
        #pragma unroll
        for (int j = 0; j < 4; ++j) {
            const int grow = brow + wr*64 + m*16 + rg*4 + j;
            float* orow = out + (size_t)grow * O_ROWS + bcol + wc*32 + cl;
            #pragma unroll
            for (int n = 0; n < 2; ++n)
                orow[n * 16] = rsqrtf(acc[m][n][j]);
        }
    }
}

extern "C" void kernel_launch(void* const* d_in, const int* in_sizes, int n_in,
                              void* d_out, int out_size, void* d_ws, size_t ws_size,
                              hipStream_t stream) {
    const float* x    = (const float*)d_in[0];
    const float* mean = (const float*)d_in[1];
    float* out = (float*)d_out;

    quadra_kernel<<<dim3((N_ROWS / 128) * (O_ROWS / 128)), 512, 0, stream>>>(
        x, mean, out);
}

// Round 15
// 45.057 us; speedup vs baseline: 2.0888x; 1.0097x over previous
//
#include <hip/hip_runtime.h>
#include <hip/hip_bf16.h>
#include <stdint.h>

#define N_ROWS 16384
#define O_ROWS 1024
#define K_DIM  512

typedef __bf16 bf16x8 __attribute__((ext_vector_type(8)));
typedef float  f32x4  __attribute__((ext_vector_type(4)));

__device__ __forceinline__ ushort f2bfu(float f) {
    __bf16 h = (__bf16)f;
    return __builtin_bit_cast(ushort, h);
}

// lgkm-only barrier: drains LDS ops, leaves global prefetch loads in flight.
#define BAR_LGKM()  do {                                        \
    asm volatile("s_waitcnt lgkmcnt(0)" ::: "memory");          \
    __builtin_amdgcn_s_barrier();                               \
} while (0)

// ---------------------------------------------------------------------------
// Round 15 = round 14 restructured to DOUBLE-BUFFERED LDS, 1 barrier per kt.
// r12/r14 (45.5-45.8 us) were phase-serialized: single-buffer forced
// write->bar->read->bar, so all waves finished MFMA before any could restage.
// Serial sum of per-CU phase costs (LDS ~20us + HBM ~16 + VALU ~8) matched
// the measured 45. With dbuf, iteration kt = {cvt+write buf[kt&1]; issue
// loads(kt+1); BAR; read buf[kt&1]+MFMA} -- no trailing barrier (next write
// targets the other buffer; lgkmcnt(0)-before-bar makes reads safe). Stage of
// fast waves overlaps MFMA of slow waves; LDS port continuously fed.
//  - 128x128 tile, BK=64, 512 thr, 2x4 wave grid, T2 swizzle, XCD swizzle,
//    extended-K-tile epilogue, reg prefetch (unroll 1). LDS 64 KB, 2 blk/CU.
// ---------------------------------------------------------------------------
__global__ __launch_bounds__(512) void quadra_kernel(
    const float* __restrict__ x, const float* __restrict__ mean,
    float* __restrict__ out)
{
    __shared__ ushort sA[2][128 * 64];   // [buf][row*64+k] bf16 (swizzled)
    __shared__ ushort sB[2][128 * 64];   // [buf][orow*64+k] bf16 (-2*mean)

    const int bid  = blockIdx.x;                // 0..1023
    const int t    = (bid & 7) * 128 + (bid >> 3);
    const int brow = (t >> 3) * 128;
    const int bcol = (t & 7) * 128;

    const int tid  = threadIdx.x;
    const int lane = tid & 63;
    const int wid  = tid >> 6;                  // 0..7
    const int wr = wid >> 2, wc = wid & 3;      // 2x4 wave grid, 64x32 out each

    f32x4 acc[4][2] = {};

    // staging: srow = tid>>3 (0..63), q = tid&7. Thread stages rows
    // {srow, srow+64}, k-octet [q*8, q*8+8) per 64-wide K-tile.
    const int srow = tid >> 3;
    const int q    = tid & 7;

    const float* gA = x    + (size_t)(brow + srow) * K_DIM + q * 8;
    const float* gB = mean + (size_t)(bcol + srow) * K_DIM + q * 8;

    float asq[2] = {0.f, 0.f}, bsq[2] = {0.f, 0.f};

    // prologue prefetch (kt = 0)
    f32x4 pa[2][2], pb[2][2];
    #pragma unroll
    for (int r2 = 0; r2 < 2; ++r2) {
        const float* pA = gA + (size_t)(r2 * 64) * K_DIM;
        const float* pB = gB + (size_t)(r2 * 64) * K_DIM;
        pa[r2][0] = *(const f32x4*)(pA);
        pa[r2][1] = *(const f32x4*)(pA + 4);
        pb[r2][0] = *(const f32x4*)(pB);
        pb[r2][1] = *(const f32x4*)(pB + 4);
    }

    const int hi = lane >> 4, cl = lane & 15;

    #pragma unroll 1
    for (int kt = 0; kt < 8; ++kt) {
        ushort* bufA = sA[kt & 1];
        ushort* bufB = sB[kt & 1];

        // consume prefetched regs: sumsq + cvt + ds_write into buf[kt&1]
        #pragma unroll
        for (int r2 = 0; r2 < 2; ++r2) {
            f32x4 a0 = pa[r2][0], a1 = pa[r2][1];
            f32x4 b0 = pb[r2][0], b1 = pb[r2][1];

            asq[r2] += a0[0]*a0[0] + a0[1]*a0[1] + a0[2]*a0[2] + a0[3]*a0[3]
                     + a1[0]*a1[0] + a1[1]*a1[1] + a1[2]*a1[2] + a1[3]*a1[3];
            bsq[r2] += b0[0]*b0[0] + b0[1]*b0[1] + b0[2]*b0[2] + b0[3]*b0[3]
                     + b1[0]*b1[0] + b1[1]*b1[1] + b1[2]*b1[2] + b1[3]*b1[3];

            bf16x8 ca, cb;
            ca[0] = (__bf16)a0[0]; ca[1] = (__bf16)a0[1];
            ca[2] = (__bf16)a0[2]; ca[3] = (__bf16)a0[3];
            ca[4] = (__bf16)a1[0]; ca[5] = (__bf16)a1[1];
            ca[6] = (__bf16)a1[2]; ca[7] = (__bf16)a1[3];
            cb[0] = (__bf16)(b0[0] * -2.0f); cb[1] = (__bf16)(b0[1] * -2.0f);
            cb[2] = (__bf16)(b0[2] * -2.0f); cb[3] = (__bf16)(b0[3] * -2.0f);
            cb[4] = (__bf16)(b1[0] * -2.0f); cb[5] = (__bf16)(b1[1] * -2.0f);
            cb[6] = (__bf16)(b1[2] * -2.0f); cb[7] = (__bf16)(b1[3] * -2.0f);

            const int row = srow + r2 * 64;
            const int wb  = (q * 16) ^ ((row & 7) << 4);   // byte offset, 16B slot
            *(bf16x8*)(bufA + row * 64 + (wb >> 1)) = ca;
            *(bf16x8*)(bufB + row * 64 + (wb >> 1)) = cb;
        }

        // issue next-tile loads: in flight across BAR + MFMA phase
        if (kt < 7) {
            #pragma unroll
            for (int r2 = 0; r2 < 2; ++r2) {
                const float* pA = gA + (size_t)(r2 * 64) * K_DIM + (kt + 1) * 64;
                const float* pB = gB + (size_t)(r2 * 64) * K_DIM + (kt + 1) * 64;
                pa[r2][0] = *(const f32x4*)(pA);
                pa[r2][1] = *(const f32x4*)(pA + 4);
                pb[r2][0] = *(const f32x4*)(pB);
                pb[r2][1] = *(const f32x4*)(pB + 4);
            }
        }

        BAR_LGKM();   // buf[kt&1] writes visible; prefetch stays in flight

        #pragma unroll
        for (int ks = 0; ks < 2; ++ks) {
            bf16x8 a[4], b[2];
            #pragma unroll
            for (int m = 0; m < 4; ++m) {
                const int row = wr*64 + m*16 + cl;
                const int rb  = (ks*64 + hi*16) ^ ((row & 7) << 4);
                a[m] = *(const bf16x8*)(bufA + row * 64 + (rb >> 1));
            }
            #pragma unroll
            for (int n = 0; n < 2; ++n) {
                const int row = wc*32 + n*16 + cl;
                const int rb  = (ks*64 + hi*16) ^ ((row & 7) << 4);
                b[n] = *(const bf16x8*)(bufB + row * 64 + (rb >> 1));
            }
            #pragma unroll
            for (int m = 0; m < 4; ++m)
                #pragma unroll
                for (int n = 0; n < 2; ++n)
                    acc[m][n] = __builtin_amdgcn_mfma_f32_16x16x32_bf16(
                        a[m], b[n], acc[m][n], 0, 0, 0);
        }
        // no trailing barrier: next iteration writes the OTHER buffer, and
        // each wave's reads here are drained by the lgkmcnt(0) in the next
        // BAR_LGKM before any wave can write this buffer again (kt+2).
    }

    // Extended K-tile, aliased into sA[0] (dead: last reads were kt=6,
    // drained before bar(7); kt=7 reads target sA[1]).
    //   sAe[row] = [xsq, 1, 0 x30]   sBe[row] = [1, msq, 0 x30]
    ushort* sAe = sA[0];
    ushort* sBe = sA[0] + 128 * 32;
    #pragma unroll
    for (int r2 = 0; r2 < 2; ++r2) {
        float sa = asq[r2], sb = bsq[r2];
        #pragma unroll
        for (int msk = 1; msk < 8; msk <<= 1) {
            sa += __shfl_xor(sa, msk);
            sb += __shfl_xor(sb, msk);
        }
        const int row = srow + r2 * 64;
        uint2 aw = {0u, 0u}, bw = {0u, 0u};
        if (q == 0) {
            aw.x = (uint32_t)f2bfu(sa) | (0x3F80u << 16);   // [xsq, 1.0]
            bw.x = 0x3F80u | ((uint32_t)f2bfu(sb) << 16);   // [1.0, msq]
        }
        *(uint2*)(sAe + row * 32 + q * 4) = aw;
        *(uint2*)(sBe + row * 32 + q * 4) = bw;
    }
    BAR_LGKM();

    {   // extra MFMA: adds xsq[r] + msq[o] into every accumulator element
        bf16x8 a[4], b[2];
        #pragma unroll
        for (int m = 0; m < 4; ++m)
            a[m] = *(const bf16x8*)(sAe + (wr*64 + m*16 + cl) * 32 + hi * 8);
        #pragma unroll
        for (int n = 0; n < 2; ++n)
            b[n] = *(const bf16x8*)(sBe + (wc*32 + n*16 + cl) * 32 + hi * 8);
        #pragma unroll
        for (int m = 0; m < 4; ++m)
            #pragma unroll
            for (int n = 0; n < 2; ++n)
                acc[m][n] = __builtin_amdgcn_mfma_f32_16x16x32_bf16(
                    a[m], b[n], acc[m][n], 0, 0, 0);
    }

    // epilogue: C/D layout col = lane&15, row = (lane>>4)*4 + j
    const int rg = lane >> 4;
    #pragma unroll
    for (int m = 0; m < 4; ++m) {
        #pragma unroll
        for (int j = 0; j < 4; ++j) {
            const int grow = brow + wr*64 + m*16 + rg*4 + j;
            float* orow = out + (size_t)grow * O_ROWS + bcol + wc*32 + cl;
            #pragma unroll
            for (int n = 0; n < 2; ++n)
                orow[n * 16] = rsqrtf(acc[m][n][j]);
        }
    }
}

extern "C" void kernel_launch(void* const* d_in, const int* in_sizes, int n_in,
                              void* d_out, int out_size, void* d_ws, size_t ws_size,
                              hipStream_t stream) {
    const float* x    = (const float*)d_in[0];
    const float* mean = (const float*)d_in[1];
    float* out = (float*)d_out;

    quadra_kernel<<<dim3((N_ROWS / 128) * (O_ROWS / 128)), 512, 0, stream>>>(
        x, mean, out);
}

// Round 16
// 40.590 us; speedup vs baseline: 2.3186x; 1.1101x over previous
//
#include <hip/hip_runtime.h>
#include <hip/hip_bf16.h>
#include <stdint.h>

#define N_ROWS 16384
#define O_ROWS 1024
#define K_DIM  512

typedef __bf16 bf16x8 __attribute__((ext_vector_type(8)));
typedef float  f32x4  __attribute__((ext_vector_type(4)));

__device__ __forceinline__ ushort f2bfu(float f) {
    __bf16 h = (__bf16)f;
    return __builtin_bit_cast(ushort, h);
}

// lgkm-only barrier (proven safe r14/r15): drains LDS ops, leaves global
// loads in flight.
#define BAR_LGKM()  do {                                        \
    asm volatile("s_waitcnt lgkmcnt(0)" ::: "memory");          \
    __builtin_amdgcn_s_barrier();                               \
} while (0)

// ---------------------------------------------------------------------------
// Round 16: BIGGER TILE (256x128), same verified machinery.
// r12/r14/r15 all ~45us across three overlap structures -> not schedule-bound;
// bound by per-unit staging VALU + LDS-port traffic. 256x128 tile with 64x64
// wave tiles cuts staged rows/output -25% and ds_read bytes/FLOP -33%.
//  - 512 thr, 8 waves (4x2), acc 4x4 frags = 64 VGPR, single-buffer 48 KB LDS.
//  - T2 XOR-swizzle on sA/sB; bijective XCD swizzle (512 blocks, 64x8 tiles);
//    extended-K-tile epilogue (d2 entirely in MFMA acc); simple staging
//    (load -> sumsq -> cvt -> ds_write), no reg-prefetch arrays (spill-safe).
// ---------------------------------------------------------------------------
__global__ __launch_bounds__(512) void quadra_kernel(
    const float* __restrict__ x, const float* __restrict__ mean,
    float* __restrict__ out)
{
    __shared__ ushort sA[256 * 64];   // [row][k] bf16 (swizzled), 32 KiB
    __shared__ ushort sB[128 * 64];   // [orow][k] bf16 -2*mean (swizzled), 16 KiB

    // XCD swizzle: 512 blocks, XCD c = bid&7 gets tiles t in [c*64, c*64+64).
    // t row-major over 64 row-panels x 8 col-tiles: 8 consecutive t share one
    // 256-row x panel -> stays in that XCD's L2.
    const int bid  = blockIdx.x;                // 0..511
    const int t    = (bid & 7) * 64 + (bid >> 3);
    const int brow = (t >> 3) * 256;
    const int bcol = (t & 7) * 128;

    const int tid  = threadIdx.x;
    const int lane = tid & 63;
    const int wid  = tid >> 6;                  // 0..7
    const int wr = wid >> 1, wc = wid & 1;      // 4x2 wave grid, 64x64 out each

    f32x4 acc[4][4] = {};

    // staging: r0 = tid>>3 (0..63), q = tid&7 (k-octet).
    // thread stages A rows {r0+64i : i=0..3} and B rows {r0+64i : i=0..1},
    // k-octet [q*8, q*8+8) per 64-wide K-tile.
    const int r0 = tid >> 3;
    const int q  = tid & 7;

    const float* gA = x    + (size_t)(brow + r0) * K_DIM + q * 8;
    const float* gB = mean + (size_t)(bcol + r0) * K_DIM + q * 8;

    float asq[4] = {0.f, 0.f, 0.f, 0.f};
    float bsq[2] = {0.f, 0.f};

    const int hi = lane >> 4, cl = lane & 15;

    #pragma unroll 1
    for (int kt = 0; kt < 8; ++kt) {
        // --- stage A (4 rows/thread) ---
        #pragma unroll
        for (int i = 0; i < 4; ++i) {
            const float* p = gA + (size_t)(i * 64) * K_DIM + kt * 64;
            f32x4 v0 = *(const f32x4*)(p);
            f32x4 v1 = *(const f32x4*)(p + 4);

            asq[i] += v0[0]*v0[0] + v0[1]*v0[1] + v0[2]*v0[2] + v0[3]*v0[3]
                    + v1[0]*v1[0] + v1[1]*v1[1] + v1[2]*v1[2] + v1[3]*v1[3];

            bf16x8 cv;
            cv[0] = (__bf16)v0[0]; cv[1] = (__bf16)v0[1];
            cv[2] = (__bf16)v0[2]; cv[3] = (__bf16)v0[3];
            cv[4] = (__bf16)v1[0]; cv[5] = (__bf16)v1[1];
            cv[6] = (__bf16)v1[2]; cv[7] = (__bf16)v1[3];

            const int row = r0 + i * 64;
            const int wb  = (q * 16) ^ ((row & 7) << 4);   // byte off, 16B slot
            *(bf16x8*)(sA + row * 64 + (wb >> 1)) = cv;
        }
        // --- stage B (2 rows/thread), scaled by -2 ---
        #pragma unroll
        for (int i = 0; i < 2; ++i) {
            const float* p = gB + (size_t)(i * 64) * K_DIM + kt * 64;
            f32x4 v0 = *(const f32x4*)(p);
            f32x4 v1 = *(const f32x4*)(p + 4);

            bsq[i] += v0[0]*v0[0] + v0[1]*v0[1] + v0[2]*v0[2] + v0[3]*v0[3]
                    + v1[0]*v1[0] + v1[1]*v1[1] + v1[2]*v1[2] + v1[3]*v1[3];

            bf16x8 cv;
            cv[0] = (__bf16)(v0[0] * -2.0f); cv[1] = (__bf16)(v0[1] * -2.0f);
            cv[2] = (__bf16)(v0[2] * -2.0f); cv[3] = (__bf16)(v0[3] * -2.0f);
            cv[4] = (__bf16)(v1[0] * -2.0f); cv[5] = (__bf16)(v1[1] * -2.0f);
            cv[6] = (__bf16)(v1[2] * -2.0f); cv[7] = (__bf16)(v1[3] * -2.0f);

            const int row = r0 + i * 64;
            const int wb  = (q * 16) ^ ((row & 7) << 4);
            *(bf16x8*)(sB + row * 64 + (wb >> 1)) = cv;
        }

        BAR_LGKM();   // staging visible

        #pragma unroll
        for (int ks = 0; ks < 2; ++ks) {
            bf16x8 a[4], b[4];
            #pragma unroll
            for (int m = 0; m < 4; ++m) {
                const int row = wr*64 + m*16 + cl;
                const int rb  = (ks*64 + hi*16) ^ ((row & 7) << 4);
                a[m] = *(const bf16x8*)(sA + row * 64 + (rb >> 1));
            }
            #pragma unroll
            for (int n = 0; n < 4; ++n) {
                const int row = wc*64 + n*16 + cl;
                const int rb  = (ks*64 + hi*16) ^ ((row & 7) << 4);
                b[n] = *(const bf16x8*)(sB + row * 64 + (rb >> 1));
            }
            #pragma unroll
            for (int m = 0; m < 4; ++m)
                #pragma unroll
                for (int n = 0; n < 4; ++n)
                    acc[m][n] = __builtin_amdgcn_mfma_f32_16x16x32_bf16(
                        a[m], b[n], acc[m][n], 0, 0, 0);
        }

        BAR_LGKM();   // reads done; next kt may overwrite
    }

    // Extended K-tile (aliased into sA, dead after the loop):
    //   sAe[row(256)] = [xsq, 1, 0 x30]   sBe[row(128)] = [1, msq, 0 x30]
    ushort* sAe = sA;              // 256*32 = 16 KB
    ushort* sBe = sA + 256 * 32;   // 128*32 =  8 KB
    #pragma unroll
    for (int i = 0; i < 4; ++i) {
        float sa = asq[i];
        #pragma unroll
        for (int msk = 1; msk < 8; msk <<= 1) sa += __shfl_xor(sa, msk);
        uint2 aw = {0u, 0u};
        if (q == 0) aw.x = (uint32_t)f2bfu(sa) | (0x3F80u << 16);  // [xsq, 1.0]
        *(uint2*)(sAe + (r0 + i * 64) * 32 + q * 4) = aw;
    }
    #pragma unroll
    for (int i = 0; i < 2; ++i) {
        float sb = bsq[i];
        #pragma unroll
        for (int msk = 1; msk < 8; msk <<= 1) sb += __shfl_xor(sb, msk);
        uint2 bw = {0u, 0u};
        if (q == 0) bw.x = 0x3F80u | ((uint32_t)f2bfu(sb) << 16);  // [1.0, msq]
        *(uint2*)(sBe + (r0 + i * 64) * 32 + q * 4) = bw;
    }
    BAR_LGKM();

    {   // extra MFMA: adds xsq[r] + msq[o] into every accumulator element
        bf16x8 a[4], b[4];
        #pragma unroll
        for (int m = 0; m < 4; ++m)
            a[m] = *(const bf16x8*)(sAe + (wr*64 + m*16 + cl) * 32 + hi * 8);
        #pragma unroll
        for (int n = 0; n < 4; ++n)
            b[n] = *(const bf16x8*)(sBe + (wc*64 + n*16 + cl) * 32 + hi * 8);
        #pragma unroll
        for (int m = 0; m < 4; ++m)
            #pragma unroll
            for (int n = 0; n < 4; ++n)
                acc[m][n] = __builtin_amdgcn_mfma_f32_16x16x32_bf16(
                    a[m], b[n], acc[m][n], 0, 0, 0);
    }

    // epilogue: C/D layout col = lane&15, row = (lane>>4)*4 + j
    const int rg = lane >> 4;
    #pragma unroll
    for (int m = 0; m < 4; ++m) {
        #pragma unroll
        for (int j = 0; j < 4; ++j) {
            const int grow = brow + wr*64 + m*16 + rg*4 + j;
            float* orow = out + (size_t)grow * O_ROWS + bcol + wc*64 + cl;
            #pragma unroll
            for (int n = 0; n < 4; ++n)
                orow[n * 16] = rsqrtf(acc[m][n][j]);
        }
    }
}

extern "C" void kernel_launch(void* const* d_in, const int* in_sizes, int n_in,
                              void* d_out, int out_size, void* d_ws, size_t ws_size,
                              hipStream_t stream) {
    const float* x    = (const float*)d_in[0];
    const float* mean = (const float*)d_in[1];
    float* out = (float*)d_out;

    quadra_kernel<<<dim3((N_ROWS / 256) * (O_ROWS / 128)), 512, 0, stream>>>(
        x, mean, out);
}